// Round 7
// baseline (268.665 us; speedup 1.0000x reference)
//
#include <hip/hip_runtime.h>
#include <math.h>

// RPNLayer: logits = x(32768,1024) @ W(1024,16) + b; per-anchor (8) 2-class
// CE over valid anchors; argmax + candidate mask.
//
// R7 = R6 (no-LDS main loop, 4 rows x 8 ch x 4 k thread tile, verified
// correct) + explicit 2-deep software pipeline. R6 stalled because the
// allocator gave the loop 52 VGPRs -> the 12 loads/iter serialized into ~4
// back-to-back ~900-cyc latencies (VALUBusy 10%). Two named prefetch buffer
// sets (A/B, 48 regs each) are loop-carried, forcing ~128+ live values: the
// compiler must issue all 12 next-slab loads before computing the current
// slab (wait becomes vmcnt(12), one latency amortized over 256 FMA cycles,
// 3 waves/EU cover the rest). waves_per_eu(3,3): 170-reg budget, no spill.
//
// d_out (float32): [0] loss | [1..262144] predict | [262145..524288] mask

#define REDSTR 20   // red row stride (floats): 80 B, 16B-aligned

__global__ __launch_bounds__(256)
__attribute__((amdgpu_waves_per_eu(3, 3)))
void rpn_main(const float* __restrict__ x, const float* __restrict__ W,
              const float* __restrict__ b, const int* __restrict__ lab,
              float* __restrict__ out, float* __restrict__ ws)
{
    __shared__ float red[32 * REDSTR];   // 2560 B
    __shared__ float lossred[2];

    const int tid = threadIdx.x;
    const int g   = tid & 15;            // k-quad: k = t*64 + g*4 + dk
    const int cg  = (tid >> 4) & 1;      // channel half: cg*8 .. cg*8+7
    const int rg  = tid >> 5;            // row group: rows rg*4 .. rg*4+3
    const int row0 = blockIdx.x * 32;

    if (tid < 2) lossred[tid] = 0.f;

    const float* xp = x + (size_t)(row0 + rg * 4) * 1024 + g * 4;
    const float* wp = W + (size_t)(g * 4) * 16 + cg * 8;

    float acc[4][8];
#pragma unroll
    for (int i = 0; i < 4; ++i)
#pragma unroll
        for (int c = 0; c < 8; ++c) acc[i][c] = 0.f;

    float4 xqA[4], waA[4], wbA[4];       // ping buffer (48 regs)
    float4 xqB[4], waB[4], wbB[4];       // pong buffer (48 regs)

    auto issue = [&](float4* bx, float4* ba, float4* bb, int t) {
#pragma unroll
        for (int i = 0; i < 4; ++i)
            bx[i] = *(const float4*)(xp + (size_t)i * 1024 + t * 64);
#pragma unroll
        for (int dk = 0; dk < 4; ++dk) {
            const float* wk = wp + (t * 64 + dk) * 16;
            ba[dk] = *(const float4*)(wk);
            bb[dk] = *(const float4*)(wk + 4);
        }
    };
    auto compute = [&](const float4* bx, const float4* ba, const float4* bb) {
#pragma unroll
        for (int i = 0; i < 4; ++i) {
            float xk[4] = {bx[i].x, bx[i].y, bx[i].z, bx[i].w};
#pragma unroll
            for (int dk = 0; dk < 4; ++dk) {
                acc[i][0] = fmaf(xk[dk], ba[dk].x, acc[i][0]);
                acc[i][1] = fmaf(xk[dk], ba[dk].y, acc[i][1]);
                acc[i][2] = fmaf(xk[dk], ba[dk].z, acc[i][2]);
                acc[i][3] = fmaf(xk[dk], ba[dk].w, acc[i][3]);
                acc[i][4] = fmaf(xk[dk], bb[dk].x, acc[i][4]);
                acc[i][5] = fmaf(xk[dk], bb[dk].y, acc[i][5]);
                acc[i][6] = fmaf(xk[dk], bb[dk].z, acc[i][6]);
                acc[i][7] = fmaf(xk[dk], bb[dk].w, acc[i][7]);
            }
        }
    };

    issue(xqA, waA, wbA, 0);
    for (int t = 0; t < 16; t += 2) {
        if (t + 1 < 16) issue(xqB, waB, wbB, t + 1);
        compute(xqA, waA, wbA);                       // waits A only; B in flight
        if (t + 2 < 16) issue(xqA, waA, wbA, t + 2);
        compute(xqB, waB, wbB);                       // waits B only; A in flight
    }

    // ---- reduce the 16 k-subgroups: butterfly over lane bits 0..3 ----
#pragma unroll
    for (int off = 1; off <= 8; off <<= 1)
#pragma unroll
        for (int i = 0; i < 4; ++i)
#pragma unroll
            for (int c = 0; c < 8; ++c)
                acc[i][c] += __shfl_xor(acc[i][c], off, 64);

    if ((tid & 15) == 0) {               // one lane per (rg, cg)
        float* rp = red + (rg * 4) * REDSTR + cg * 8;
#pragma unroll
        for (int i = 0; i < 4; ++i) {
            *(float4*)(rp + i * REDSTR)     = make_float4(acc[i][0], acc[i][1], acc[i][2], acc[i][3]);
            *(float4*)(rp + i * REDSTR + 4) = make_float4(acc[i][4], acc[i][5], acc[i][6], acc[i][7]);
        }
    }
    __syncthreads();

    // ---- epilogue (verified R6): thread = (row = tid>>3, anchor a = tid&7) ----
    {
        const int row = tid >> 3;
        const int a   = tid & 7;
        float l0 = red[row * REDSTR + 2 * a]     + b[2 * a];
        float l1 = red[row * REDSTR + 2 * a + 1] + b[2 * a + 1];

        int lb = lab[(size_t)row0 * 8 + tid];
        int pred  = (l1 > l0) ? 1 : 0;           // strict: tie -> class 0
        int valid = (lb != -1);
        float m   = fmaxf(l0, l1);
        float lse = m + logf(expf(l0 - m) + expf(l1 - m));
        float nll = lse - ((lb == 1) ? l1 : l0);
        float ls = valid ? nll : 0.f;
        float lc = valid ? 1.f : 0.f;
        out[1 + (size_t)row0 * 8 + tid] = (float)pred;
        out[1 + 262144 + (size_t)row0 * 8 + tid] = (pred && valid) ? 1.f : 0.f;
#pragma unroll
        for (int off = 32; off > 0; off >>= 1) {
            ls += __shfl_down(ls, off);
            lc += __shfl_down(lc, off);
        }
        if ((tid & 63) == 0) {
            atomicAdd(&lossred[0], ls);
            atomicAdd(&lossred[1], lc);
        }
    }
    __syncthreads();
    if (tid == 0) {
        atomicAdd(&ws[0], lossred[0]);
        atomicAdd(&ws[1], lossred[1]);
    }
}

__global__ void rpn_final(const float* __restrict__ ws, float* __restrict__ out)
{
    out[0] = ws[0] / fmaxf(ws[1], 1.f);
}

extern "C" void kernel_launch(void* const* d_in, const int* in_sizes, int n_in,
                              void* d_out, int out_size, void* d_ws, size_t ws_size,
                              hipStream_t stream)
{
    const float* x   = (const float*)d_in[0];   // (64,512,1024) f32
    const float* W   = (const float*)d_in[1];   // (1024,16) f32
    const float* b   = (const float*)d_in[2];   // (16,) f32
    const int*   lab = (const int*)d_in[3];     // (64,512,8) i32 in {-1,0,1}
    float* out = (float*)d_out;
    float* ws  = (float*)d_ws;

    hipMemsetAsync(ws, 0, 2 * sizeof(float), stream);
    rpn_main<<<dim3(1024), dim3(256), 0, stream>>>(x, W, b, lab, out, ws);
    rpn_final<<<dim3(1), dim3(1), 0, stream>>>(ws, out);
}